// Round 9
// baseline (228.467 us; speedup 1.0000x reference)
//
#include <hip/hip_runtime.h>
#include <hip/hip_bf16.h>
#include <cstdint>
#include <cstddef>

#define LAYERS 3
#define EMB 256
#define NB 4096
#define MAXLEN 50
#define NITEMS 50000

typedef float f32x4 __attribute__((ext_vector_type(4)));
typedef __bf16 bf16x8 __attribute__((ext_vector_type(8)));
typedef unsigned short u16;

static __device__ __forceinline__ u16 f2bf(float f) {
  union { float f; uint32_t u; } v; v.f = f;
  uint32_t r = v.u + 0x7FFFu + ((v.u >> 16) & 1u);
  return (u16)(r >> 16);
}

static __device__ __forceinline__ float bf2f(u16 h) {
  union { uint32_t u; float f; } v; v.u = (uint32_t)h << 16; return v.f;
}

static __device__ __forceinline__ f32x4 bfu4(ushort4 h) {
  f32x4 r; r.x = bf2f(h.x); r.y = bf2f(h.y); r.z = bf2f(h.z); r.w = bf2f(h.w);
  return r;
}

static __device__ __forceinline__ ushort4 f2bf4(f32x4 v) {
  ushort4 o; o.x = f2bf(v.x); o.y = f2bf(v.y); o.z = f2bf(v.z); o.w = f2bf(v.w);
  return o;
}

template <typename T> __device__ __forceinline__ T cvt_out(float v);
template <> __device__ __forceinline__ float cvt_out<float>(float v) { return v; }
template <> __device__ __forceinline__ u16 cvt_out<u16>(float v) { return f2bf(v); }

// ---------------- pack w -> bf16 (only remaining pack; 1.5 MB) ----------------
__global__ void pack_w(const float* __restrict__ in, u16* __restrict__ out) {
  int i = blockIdx.x * blockDim.x + threadIdx.x;
  reinterpret_cast<ushort4*>(out)[i] = f2bf4(reinterpret_cast<const f32x4*>(in)[i]);
}

// ---------------- gather + mean pool (1 wave/session, f32 table, 5-deep MLP) ----------------
// pad handled by clamped address + 0/1 multiplier (no divergent branch, loads batched)
__global__ void gather_mean(const float* __restrict__ emb, const int* __restrict__ items,
                            const float* __restrict__ slen, float* __restrict__ acc,
                            u16* __restrict__ xb) {
  int w = threadIdx.x >> 6, lane = threadIdx.x & 63;
  int b = blockIdx.x * 4 + w;
  f32x4 s = {0.f, 0.f, 0.f, 0.f};
  const int* it = items + (size_t)b * MAXLEN;
  const int le = lane * 4;
#pragma unroll 2
  for (int l = 0; l < MAXLEN; l += 5) {
    int i0 = it[l], i1 = it[l + 1], i2 = it[l + 2], i3 = it[l + 3], i4 = it[l + 4];
    f32x4 v0 = *reinterpret_cast<const f32x4*>(emb + (size_t)(i0 > 0 ? i0 - 1 : 0) * EMB + le);
    f32x4 v1 = *reinterpret_cast<const f32x4*>(emb + (size_t)(i1 > 0 ? i1 - 1 : 0) * EMB + le);
    f32x4 v2 = *reinterpret_cast<const f32x4*>(emb + (size_t)(i2 > 0 ? i2 - 1 : 0) * EMB + le);
    f32x4 v3 = *reinterpret_cast<const f32x4*>(emb + (size_t)(i3 > 0 ? i3 - 1 : 0) * EMB + le);
    f32x4 v4 = *reinterpret_cast<const f32x4*>(emb + (size_t)(i4 > 0 ? i4 - 1 : 0) * EMB + le);
    s += v0 * (i0 > 0 ? 1.f : 0.f) + v1 * (i1 > 0 ? 1.f : 0.f) + v2 * (i2 > 0 ? 1.f : 0.f) +
         v3 * (i3 > 0 ? 1.f : 0.f) + v4 * (i4 > 0 ? 1.f : 0.f);
  }
  float inv = 1.0f / slen[b];
  s *= inv;
  *reinterpret_cast<f32x4*>(acc + (size_t)b * EMB + le) = s;
  *reinterpret_cast<ushort4*>(xb + (size_t)b * EMB + le) = f2bf4(s);
}

// ---------------- mixed-dtype staging helpers (XOR-swizzled, both-sides rule) ----------------
// LDS content[r][c] = global[r][c ^ (r&7)] in 16B chunks; linear LDS dest, swizzled source.
template <bool F32>
__device__ __forceinline__ void stage_tile(const void* __restrict__ g, char* lds, int rbase,
                                           int K, int k0, int tid, int wid) {
  constexpr int CPR = F32 ? 16 : 8;   // 16B chunks per row (row = 64 elems)
  constexpr int NLD = F32 ? 8 : 4;    // loads per thread (128 rows)
#pragma unroll
  for (int i = 0; i < NLD; i++) {
    int row = i * (256 / CPR) + (tid / CPR);
    int sc = (tid % CPR) ^ (row & 7);
    if constexpr (F32) {
      const float* src = (const float*)g + (size_t)(rbase + row) * K + k0 + sc * 4;
      __builtin_amdgcn_global_load_lds(
          (const __attribute__((address_space(1))) void*)src,
          (__attribute__((address_space(3))) void*)(lds + (i * 256 + wid * 64) * 16), 16, 0, 0);
    } else {
      const u16* src = (const u16*)g + (size_t)(rbase + row) * K + k0 + sc * 8;
      __builtin_amdgcn_global_load_lds(
          (const __attribute__((address_space(1))) void*)src,
          (__attribute__((address_space(3))) void*)(lds + (i * 256 + wid * 64) * 16), 16, 0, 0);
    }
  }
}

// read one MFMA frag (8 bf16 at k-offset kk*32 + lhi*8) from a swizzled BK=64 tile
template <bool F32>
__device__ __forceinline__ bf16x8 ld_frag(const char* lds, int row_, int kk, int lhi, int sw7) {
  if constexpr (F32) {
    const float* p = (const float*)lds + (size_t)row_ * 64;
    int cp = kk * 8 + lhi * 2;
    f32x4 lo = *reinterpret_cast<const f32x4*>(p + ((cp ^ sw7) * 4));
    f32x4 hi = *reinterpret_cast<const f32x4*>(p + (((cp + 1) ^ sw7) * 4));
    bf16x8 r;
    r[0] = (__bf16)lo[0]; r[1] = (__bf16)lo[1]; r[2] = (__bf16)lo[2]; r[3] = (__bf16)lo[3];
    r[4] = (__bf16)hi[0]; r[5] = (__bf16)hi[1]; r[6] = (__bf16)hi[2]; r[7] = (__bf16)hi[3];
    return r;
  } else {
    const u16* p = (const u16*)lds + (size_t)row_ * 64;
    int co = ((kk * 4 + lhi) ^ sw7) * 8;
    return *reinterpret_cast<const bf16x8*>(p + co);
  }
}

// ---------------- GEMM 128x128, BK=64, mixed f32/bf16 operands, split-K via blockIdx.z ----
// C[M][N] = sum_k A[m][k]*B[n][k]; f32 operands converted to bf16 (RNE) at frag build.
template <bool AF32, bool BF32, typename OUT_T>
__global__ __launch_bounds__(256, 3) void gemm_mx(const void* __restrict__ Av,
                                                  const void* __restrict__ Bv,
                                                  OUT_T* __restrict__ C,
                                                  int M, int N, int K, size_t zstride) {
  __shared__ __align__(16) char As[128 * 64 * (AF32 ? 4 : 2)];
  __shared__ __align__(16) char Bs[128 * 64 * (BF32 ? 4 : 2)];
  const int tid = threadIdx.x;
  const int lane = tid & 63;
  const int wid = tid >> 6;
  const int wr = wid >> 1, wc = wid & 1;  // 2x2 waves, 64x64 each
  const int row0 = blockIdx.y * 128, col0 = blockIdx.x * 128;
  const int kslice = K / (int)gridDim.z;
  const int kb = blockIdx.z * kslice, ke = kb + kslice;
  C += (size_t)blockIdx.z * zstride;

  f32x4 acc[4][4];
#pragma unroll
  for (int m = 0; m < 4; m++)
#pragma unroll
    for (int n = 0; n < 4; n++)
#pragma unroll
      for (int j = 0; j < 4; j++) acc[m][n][j] = 0.0f;

  const int lrow = lane & 15;
  const int lhi = lane >> 4;
  const int sw7 = lane & 7;  // == (frag row)&7 since frag rows = multiple-of-8 + lrow

  for (int k0 = kb; k0 < ke; k0 += 64) {
    stage_tile<AF32>(Av, As, row0, K, k0, tid, wid);
    stage_tile<BF32>(Bv, Bs, col0, K, k0, tid, wid);
    __syncthreads();

#pragma unroll
    for (int kk = 0; kk < 2; kk++) {
      bf16x8 af[4], bfv[4];
#pragma unroll
      for (int m = 0; m < 4; m++)
        af[m] = ld_frag<AF32>(As, wr * 64 + m * 16 + lrow, kk, lhi, sw7);
#pragma unroll
      for (int n = 0; n < 4; n++)
        bfv[n] = ld_frag<BF32>(Bs, wc * 64 + n * 16 + lrow, kk, lhi, sw7);
#pragma unroll
      for (int m = 0; m < 4; m++)
#pragma unroll
        for (int n = 0; n < 4; n++)
          acc[m][n] = __builtin_amdgcn_mfma_f32_16x16x32_bf16(af[m], bfv[n], acc[m][n], 0, 0, 0);
    }
    __syncthreads();
  }

#pragma unroll
  for (int m = 0; m < 4; m++) {
#pragma unroll
    for (int j = 0; j < 4; j++) {
      int r = row0 + wr * 64 + m * 16 + lhi * 4 + j;
      OUT_T* cp = C + (size_t)r * N + col0 + wc * 64 + lrow;
#pragma unroll
      for (int n = 0; n < 4; n++) cp[n * 16] = cvt_out<OUT_T>(acc[m][n][j]);
    }
  }
}

// ---------------- GEMM 64x64, K=256 staged in ONE shot (single barrier) ----------------
// yT[e][b] = sum_f W[e][f] * x[b][f]; both operands bf16 row-major, K=EMB=256.
__global__ __launch_bounds__(256) void gemm64_ss(const u16* __restrict__ Am,
                                                 const u16* __restrict__ Bt,
                                                 u16* __restrict__ C, int N) {
  __shared__ __align__(16) u16 As[64 * 256];
  __shared__ __align__(16) u16 Bs[64 * 256];
  const int tid = threadIdx.x;
  const int lane = tid & 63;
  const int wid = tid >> 6;
  const int wr = wid >> 1, wc = wid & 1;  // 2x2 waves, 32x32 each
  const int row0 = blockIdx.y * 64, col0 = blockIdx.x * 64;
  const int lrow = lane & 15;
  const int lhi = lane >> 4;
  const int sw7 = lane & 7;

  // stage 64x256 tiles (32 KB each): 8 x 16B loads/thread/operand; chunk^=(row&7)
#pragma unroll
  for (int i = 0; i < 8; i++) {
    int row = i * 8 + (tid >> 5);
    int sc = (tid & 31) ^ (row & 7);
    __builtin_amdgcn_global_load_lds(
        (const __attribute__((address_space(1))) void*)(Am + (size_t)(row0 + row) * EMB + sc * 8),
        (__attribute__((address_space(3))) void*)((char*)As + (i * 256 + wid * 64) * 16), 16, 0, 0);
    __builtin_amdgcn_global_load_lds(
        (const __attribute__((address_space(1))) void*)(Bt + (size_t)(col0 + row) * EMB + sc * 8),
        (__attribute__((address_space(3))) void*)((char*)Bs + (i * 256 + wid * 64) * 16), 16, 0, 0);
  }
  __syncthreads();

  f32x4 acc[2][2];
#pragma unroll
  for (int m = 0; m < 2; m++)
#pragma unroll
    for (int n = 0; n < 2; n++)
#pragma unroll
      for (int j = 0; j < 4; j++) acc[m][n][j] = 0.0f;

#pragma unroll
  for (int ks = 0; ks < 8; ks++) {
    const int co = ((ks * 4 + lhi) ^ sw7) * 8;
    bf16x8 af[2], bfv[2];
#pragma unroll
    for (int m = 0; m < 2; m++)
      af[m] = *reinterpret_cast<const bf16x8*>(As + (size_t)(wr * 32 + m * 16 + lrow) * 256 + co);
#pragma unroll
    for (int n = 0; n < 2; n++)
      bfv[n] = *reinterpret_cast<const bf16x8*>(Bs + (size_t)(wc * 32 + n * 16 + lrow) * 256 + co);
#pragma unroll
    for (int m = 0; m < 2; m++)
#pragma unroll
      for (int n = 0; n < 2; n++)
        acc[m][n] = __builtin_amdgcn_mfma_f32_16x16x32_bf16(af[m], bfv[n], acc[m][n], 0, 0, 0);
  }

#pragma unroll
  for (int m = 0; m < 2; m++) {
#pragma unroll
    for (int j = 0; j < 4; j++) {
      int r = row0 + wr * 32 + m * 16 + lhi * 4 + j;
      u16* cp = C + (size_t)r * N + col0 + wc * 32 + lrow;
#pragma unroll
      for (int n = 0; n < 2; n++) cp[n * 16] = f2bf(acc[m][n][j]);
    }
  }
}

// ---------------- sum bf16 split-K partials -> bf16 (for uT) ----------------
__global__ void uredux(const u16* __restrict__ zp, u16* __restrict__ uT,
                       int n4, int nsplit, size_t zstride4) {
  int i = blockIdx.x * blockDim.x + threadIdx.x;
  if (i < n4) {
    f32x4 s = {0.f, 0.f, 0.f, 0.f};
    for (int k = 0; k < nsplit; k++)
      s += bfu4(reinterpret_cast<const ushort4*>(zp)[(size_t)k * zstride4 + i]);
    reinterpret_cast<ushort4*>(uT)[i] = f2bf4(s);
  }
}

// ---------------- bf16 split-K reduce + row norm + accumulate (+final scale) ----------------
__global__ void norm_acc(const u16* __restrict__ zp, size_t zstride, int nsplit,
                         float* __restrict__ acc, u16* __restrict__ xb,
                         float* __restrict__ outp, int fin) {
  int b = blockIdx.x, t = threadIdx.x;
  size_t i = (size_t)b * EMB + t;
  float v = 0.0f;
  for (int s = 0; s < nsplit; s++) v += bf2f(zp[(size_t)s * zstride + i]);
  float s2 = v * v;
#pragma unroll
  for (int o = 32; o > 0; o >>= 1) s2 += __shfl_down(s2, o, 64);
  __shared__ float ws4[4];
  if ((t & 63) == 0) ws4[t >> 6] = s2;
  __syncthreads();
  float tot = ws4[0] + ws4[1] + ws4[2] + ws4[3];
  float rn = 1.0f / fmaxf(sqrtf(tot), 1e-12f);
  if (fin) {
    outp[i] = (acc[i] + v * rn) * 0.25f;
  } else {
    acc[i] += v * rn;
    xb[i] = f2bf(v);
  }
}

// ---------------- launch ----------------
// Per layer (associativity rewrite: DA@(xW^T) == D@(A@(xW^T)), 3.2x fewer FLOPs).
// D and A are consumed as raw f32 (staged f32 into LDS, cvt to bf16 at frag build) —
// no 128 MB pack pass, no bf16 copies of D/A in workspace.
extern "C" void kernel_launch(void* const* d_in, const int* in_sizes, int n_in,
                              void* d_out, int out_size, void* d_ws, size_t ws_size,
                              hipStream_t stream) {
  const float* emb   = (const float*)d_in[0];
  const float* D     = (const float*)d_in[1];
  const float* A     = (const float*)d_in[2];
  const int*   items = (const int*)d_in[3];
  const float* slen  = (const float*)d_in[4];
  const float* w     = (const float*)d_in[5];
  float* out = (float*)d_out;

  // workspace carve (~26.4 MB)
  char* p = (char*)d_ws;
  u16* zp   = (u16*)p;   p += (size_t)8 * NB * EMB * 2;        // 16 MB splitK partials
  float* accf = (float*)p; p += (size_t)NB * EMB * 4;          // 4 MB
  u16* xb   = (u16*)p;   p += (size_t)NB * EMB * 2;            // 2 MB
  u16* yT   = (u16*)p;   p += (size_t)EMB * NB * 2;            // 2 MB
  u16* uT   = (u16*)p;   p += (size_t)EMB * NB * 2;            // 2 MB
  u16* wb   = (u16*)p;   p += (size_t)LAYERS * EMB * EMB * 2;  // 0.4 MB

  pack_w<<<LAYERS * EMB * EMB / 4 / 256, 256, 0, stream>>>(w, wb);
  gather_mean<<<NB / 4, 256, 0, stream>>>(emb, items, slen, accf, xb);

  for (int i = 0; i < LAYERS; i++) {
    // yT[e][b] = sum_f W[e][f] * x[b][f]   (single-stage 64x64, one barrier)
    gemm64_ss<<<dim3(NB / 64, EMB / 64), 256, 0, stream>>>(wb + (size_t)i * EMB * EMB, xb, yT,
                                                           NB);
    // uT partials: zp[s][e][b] = partial_j yT[e][j] * A[b][j]   (A read as f32)
    gemm_mx<false, true, u16><<<dim3(NB / 128, EMB / 128, 8), 256, 0, stream>>>(
        yT, A, zp, EMB, NB, NB, (size_t)EMB * NB);
    // uT = bf16(sum partials)
    uredux<<<EMB * NB / 4 / 256, 256, 0, stream>>>(zp, uT, EMB * NB / 4, 8,
                                                   (size_t)EMB * NB / 4);
    // z partials: zp[s][b][e] = partial_j D[b][j] * uT[e][j]    (D read as f32)
    gemm_mx<true, false, u16><<<dim3(EMB / 128, NB / 128, 8), 256, 0, stream>>>(
        D, uT, zp, NB, EMB, NB, (size_t)NB * EMB);
    // v = sum partials; acc += v/||v||; xb = bf16(v); final: out = 0.25*(acc+v/||v||)
    norm_acc<<<NB, 256, 0, stream>>>(zp, (size_t)NB * EMB, 8, accf, xb, out, i == LAYERS - 1);
  }
}